// Round 6
// baseline (425.095 us; speedup 1.0000x reference)
//
#include <hip/hip_runtime.h>

#define HH 16
#define RED_VALS 34   // 16 top(g.p) + 16 (y.p) + cur + gg
#define OUTBLK 2048

// Straight-line reduction: ONE float4 chunk per thread (no grid-stride loop).
// All 33 loads issue as a single burst (sched_barrier pins them above the
// FMAs) — mirrors the output kernel's structure, which streams at 6.8 TB/s.
// Epilogue: wave shuffle + LDS cross-wave; block writes 34 partials
// column-major [RED_VALS][nblk] so the solve kernel reads coalesced.
__global__ __launch_bounds__(256) void lbfgs_reduce_line(
    const float* __restrict__ p, const float* __restrict__ y,
    const float* __restrict__ g, const int* __restrict__ idxp,
    float* __restrict__ partials, int nblk, int n) {
  const int c = blockIdx.x * 256 + threadIdx.x;
  const int nchunk = n >> 2;
  const int is = idxp[0];
  const int hidx = ((is - 1) % HH + HH) % HH;

  float accg[HH], accy[HH];
#pragma unroll
  for (int i = 0; i < HH; ++i) { accg[i] = 0.f; accy[i] = 0.f; }
  float ac = 0.f, agg = 0.f;

  if (c < nchunk) {
    const float4 pv = reinterpret_cast<const float4*>(p)[c];
    float4 gv[HH], yv[HH];
#pragma unroll
    for (int i = 0; i < HH; ++i)
      gv[i] = reinterpret_cast<const float4*>(g + (size_t)i * n)[c];
#pragma unroll
    for (int i = 0; i < HH; ++i)
      yv[i] = reinterpret_cast<const float4*>(y + (size_t)i * n)[c];
    __builtin_amdgcn_sched_barrier(0);  // keep all 33 loads above the FMAs
#pragma unroll
    for (int i = 0; i < HH; ++i) {
      accg[i] = gv[i].x * pv.x + gv[i].y * pv.y + gv[i].z * pv.z + gv[i].w * pv.w;
      accy[i] = yv[i].x * pv.x + yv[i].y * pv.y + yv[i].z * pv.z + yv[i].w * pv.w;
      float dyg = yv[i].x * gv[i].x + yv[i].y * gv[i].y +
                  yv[i].z * gv[i].z + yv[i].w * gv[i].w;
      float dgg = gv[i].x * gv[i].x + gv[i].y * gv[i].y +
                  gv[i].z * gv[i].z + gv[i].w * gv[i].w;
      ac  += (i == hidx) ? dyg : 0.f;   // branchless select, hidx wave-uniform
      agg += (i == hidx) ? dgg : 0.f;
    }
  }
  // scalar remainder (n % 4 != 0), handled by block 0 only
  if (blockIdx.x == 0) {
    for (int e = (nchunk << 2) + threadIdx.x; e < n; e += 256) {
      float pv = p[e];
#pragma unroll
      for (int i = 0; i < HH; ++i) {
        float gs = g[(size_t)i * n + e], ys = y[(size_t)i * n + e];
        accg[i] += gs * pv;
        accy[i] += ys * pv;
        ac  += (i == hidx) ? ys * gs : 0.f;
        agg += (i == hidx) ? gs * gs : 0.f;
      }
    }
  }

  // wave(64) shuffle reduce, then cross-wave via LDS, block writes 34 values
  __shared__ float red[4][RED_VALS];
  const int wave = threadIdx.x >> 6, lane = threadIdx.x & 63;
#pragma unroll
  for (int i = 0; i < HH; ++i) {
    float v = accg[i];
#pragma unroll
    for (int off = 32; off > 0; off >>= 1) v += __shfl_down(v, off);
    if (lane == 0) red[wave][i] = v;
    float w = accy[i];
#pragma unroll
    for (int off = 32; off > 0; off >>= 1) w += __shfl_down(w, off);
    if (lane == 0) red[wave][HH + i] = w;
  }
  {
    float v = ac;
#pragma unroll
    for (int off = 32; off > 0; off >>= 1) v += __shfl_down(v, off);
    if (lane == 0) red[wave][32] = v;
    float w = agg;
#pragma unroll
    for (int off = 32; off > 0; off >>= 1) w += __shfl_down(w, off);
    if (lane == 0) red[wave][33] = w;
  }
  __syncthreads();
  if (threadIdx.x < RED_VALS) {
    float s = red[0][threadIdx.x] + red[1][threadIdx.x] +
              red[2][threadIdx.x] + red[3][threadIdx.x];
    partials[(size_t)threadIdx.x * nblk + blockIdx.x] = s;
  }
}

// Fallback (small ws_size): R1-style grid-stride loop, 1024 blocks.
__global__ __launch_bounds__(256) void lbfgs_reduce_loop(
    const float* __restrict__ p, const float* __restrict__ y,
    const float* __restrict__ g, const int* __restrict__ idxp,
    float* __restrict__ partials, int nblk, int n) {
  const int is = idxp[0];
  const int hidx = ((is - 1) % HH + HH) % HH;
  float acc[RED_VALS];
#pragma unroll
  for (int j = 0; j < RED_VALS; ++j) acc[j] = 0.f;

  const int tid = blockIdx.x * blockDim.x + threadIdx.x;
  const int nth = gridDim.x * blockDim.x;
  const int nchunk = n >> 2;
  const float4* __restrict__ p4 = reinterpret_cast<const float4*>(p);

  for (int c = tid; c < nchunk; c += nth) {
    float4 pv = p4[c];
#pragma unroll
    for (int i = 0; i < HH; ++i) {
      const float4 gv = reinterpret_cast<const float4*>(g + (size_t)i * n)[c];
      const float4 yv = reinterpret_cast<const float4*>(y + (size_t)i * n)[c];
      acc[i]      += gv.x * pv.x + gv.y * pv.y + gv.z * pv.z + gv.w * pv.w;
      acc[HH + i] += yv.x * pv.x + yv.y * pv.y + yv.z * pv.z + yv.w * pv.w;
      if (i == hidx) {
        acc[32] += yv.x * gv.x + yv.y * gv.y + yv.z * gv.z + yv.w * gv.w;
        acc[33] += gv.x * gv.x + gv.y * gv.y + gv.z * gv.z + gv.w * gv.w;
      }
    }
  }
  for (int c = (nchunk << 2) + tid; c < n; c += nth) {
    float pv = p[c];
#pragma unroll
    for (int i = 0; i < HH; ++i) {
      float gv = g[(size_t)i * n + c];
      float yv = y[(size_t)i * n + c];
      acc[i] += gv * pv;
      acc[HH + i] += yv * pv;
      if (i == hidx) { acc[32] += yv * gv; acc[33] += gv * gv; }
    }
  }
#pragma unroll
  for (int j = 0; j < RED_VALS; ++j) {
    float v = acc[j];
#pragma unroll
    for (int off = 32; off > 0; off >>= 1) v += __shfl_down(v, off);
    acc[j] = v;
  }
  __shared__ float red[4][RED_VALS];
  const int wave = threadIdx.x >> 6, lane = threadIdx.x & 63;
  if (lane == 0) {
#pragma unroll
    for (int j = 0; j < RED_VALS; ++j) red[wave][j] = acc[j];
  }
  __syncthreads();
  if (threadIdx.x < RED_VALS) {
    float s = red[0][threadIdx.x] + red[1][threadIdx.x] +
              red[2][threadIdx.x] + red[3][threadIdx.x];
    partials[(size_t)threadIdx.x * nblk + blockIdx.x] = s;
  }
}

__global__ __launch_bounds__(256) void lbfgs_solve(
    const float* __restrict__ partials, int nblkp,
    const float* __restrict__ Lmat, const float* __restrict__ diag,
    const float* __restrict__ sinner, const int* __restrict__ idxp,
    float* __restrict__ coeff) {
  __shared__ float sums[RED_VALS];
  __shared__ float wred[RED_VALS][4];
  const int wave = threadIdx.x >> 6, lane = threadIdx.x & 63;
  for (int j = 0; j < RED_VALS; ++j) {
    float v = 0.f;
    for (int b = threadIdx.x; b < nblkp; b += 256)
      v += partials[(size_t)j * nblkp + b];
#pragma unroll
    for (int off = 32; off > 0; off >>= 1) v += __shfl_down(v, off);
    if (lane == 0) wred[j][wave] = v;
  }
  __syncthreads();
  if (threadIdx.x < RED_VALS)
    sums[threadIdx.x] = wred[threadIdx.x][0] + wred[threadIdx.x][1] +
                        wred[threadIdx.x][2] + wred[threadIdx.x][3];
  __syncthreads();

  __shared__ float Lsh[HH][HH];
  __shared__ float dd[HH], sqd[HH];
  __shared__ float Jsq[HH][HH];
  __shared__ float gamma_s;
  __shared__ float x[2 * HH];
  {
    int i = threadIdx.x >> 4, j = threadIdx.x & 15;
    if (threadIdx.x < 256) Lsh[i][j] = Lmat[i * HH + j];
  }
  if (threadIdx.x < HH) {
    float dv = diag[threadIdx.x];
    float ddv = (dv == 0.f) ? 1.f : dv;
    dd[threadIdx.x] = ddv;
    sqd[threadIdx.x] = sqrtf(ddv);
  }
  if (threadIdx.x == 0) {
    float cur = sums[32], gg = sums[33];
    gamma_s = (cur > 0.f) ? (gg / cur) : 1.f;
  }
  __syncthreads();
  {
    int i = threadIdx.x >> 4, j = threadIdx.x & 15;
    float v = gamma_s * sinner[i * HH + j];
#pragma unroll
    for (int k = 0; k < HH; ++k) v += Lsh[i][k] * Lsh[j][k] / dd[k];
    Jsq[i][j] = v;
  }
  __syncthreads();
  if (threadIdx.x == 0) {
    // in-place lower Cholesky of Jsq (16x16, serial — tiny)
    for (int c = 0; c < HH; ++c) {
      float s = Jsq[c][c];
      for (int k = 0; k < c; ++k) s -= Jsq[c][k] * Jsq[c][k];
      float dv = sqrtf(s);
      Jsq[c][c] = dv;
      float inv = 1.f / dv;
      for (int r = c + 1; r < HH; ++r) {
        float s2 = Jsq[r][c];
        for (int k = 0; k < c; ++k) s2 -= Jsq[r][k] * Jsq[c][k];
        Jsq[r][c] = s2 * inv;
      }
    }
    const int is = idxp[0];
    const int sh = (is <= HH) ? 0 : (is % HH);
    const float gamma = gamma_s;
    // build rolled descent vector
    for (int k = 0; k < HH; ++k) {
      x[k]      = sums[(k + sh) & (HH - 1)];
      x[HH + k] = gamma * sums[HH + ((k + sh) & (HH - 1))];
    }
    // forward solve: low_tri = [[diag(sqd), 0], [-L/sqd_col, J]]
    for (int i = 0; i < HH; ++i) x[i] /= sqd[i];
    for (int i = 0; i < HH; ++i) {
      float s = x[HH + i];
      for (int j = 0; j < HH; ++j) s += (Lsh[i][j] / sqd[j]) * x[j];
      for (int j = 0; j < i; ++j) s -= Jsq[i][j] * x[HH + j];
      x[HH + i] = s / Jsq[i][i];
    }
    // backward solve: upper = low^T with top h rows negated
    for (int i = HH - 1; i >= 0; --i) {
      float s = x[HH + i];
      for (int j = i + 1; j < HH; ++j) s -= Jsq[j][i] * x[HH + j];
      x[HH + i] = s / Jsq[i][i];
    }
    for (int i = 0; i < HH; ++i) {
      float s = x[i];
      for (int j = 0; j < HH; ++j) s -= (Lsh[j][i] / sqd[i]) * x[HH + j];
      x[i] = s / (-sqd[i]);
    }
    // un-roll and emit coefficients (beta pre-scaled by gamma)
    coeff[0] = gamma;
    for (int k = 0; k < HH; ++k) {
      coeff[1 + k]      = x[(k - sh + HH) & (HH - 1)];
      coeff[1 + HH + k] = gamma * x[HH + ((k - sh + HH) & (HH - 1))];
    }
  }
}

// Plain ascending grid-stride (proven ~6.8 TB/s form).
__global__ __launch_bounds__(256) void lbfgs_output(
    const float* __restrict__ p, const float* __restrict__ y,
    const float* __restrict__ g, const float* __restrict__ coeff,
    float* __restrict__ out, int n) {
  const float gamma = coeff[0];
  float a[HH], b[HH];
#pragma unroll
  for (int i = 0; i < HH; ++i) {
    a[i] = coeff[1 + i];
    b[i] = coeff[1 + HH + i];
  }
  const int tid = blockIdx.x * blockDim.x + threadIdx.x;
  const int nth = gridDim.x * blockDim.x;
  const int nchunk = n >> 2;
  const float4* __restrict__ p4 = reinterpret_cast<const float4*>(p);
  float4* __restrict__ out4 = reinterpret_cast<float4*>(out);
  for (int c = tid; c < nchunk; c += nth) {
    float4 pv = p4[c];
    float ox = gamma * pv.x, oy = gamma * pv.y;
    float oz = gamma * pv.z, ow = gamma * pv.w;
#pragma unroll
    for (int i = 0; i < HH; ++i) {
      const float4 gv = reinterpret_cast<const float4*>(g + (size_t)i * n)[c];
      const float4 yv = reinterpret_cast<const float4*>(y + (size_t)i * n)[c];
      ox -= a[i] * gv.x + b[i] * yv.x;
      oy -= a[i] * gv.y + b[i] * yv.y;
      oz -= a[i] * gv.z + b[i] * yv.z;
      ow -= a[i] * gv.w + b[i] * yv.w;
    }
    out4[c] = make_float4(ox, oy, oz, ow);
  }
  for (int c = (nchunk << 2) + tid; c < n; c += nth) {
    float pv = p[c];
    float o = gamma * pv;
#pragma unroll
    for (int i = 0; i < HH; ++i)
      o -= a[i] * g[(size_t)i * n + c] + b[i] * y[(size_t)i * n + c];
    out[c] = o;
  }
}

extern "C" void kernel_launch(void* const* d_in, const int* in_sizes, int n_in,
                              void* d_out, int out_size, void* d_ws, size_t ws_size,
                              hipStream_t stream) {
  const float* p      = (const float*)d_in[0];
  const float* y      = (const float*)d_in[1];
  const float* g      = (const float*)d_in[2];
  const float* Lmat   = (const float*)d_in[3];
  const float* diag   = (const float*)d_in[4];
  const float* sinner = (const float*)d_in[5];
  const int*   idxp   = (const int*)d_in[6];
  float* out = (float*)d_out;
  float* wsf = (float*)d_ws;
  const int n = in_sizes[0];

  const int nchunk = n >> 2;
  const int nblk_line = (nchunk + 255) / 256;  // one chunk per thread
  const size_t need_line = ((size_t)RED_VALS * nblk_line + 64) * sizeof(float);

  if (ws_size >= need_line) {
    float* partials = wsf;
    float* coeff = wsf + (size_t)RED_VALS * nblk_line;
    lbfgs_reduce_line<<<dim3(nblk_line), dim3(256), 0, stream>>>(
        p, y, g, idxp, partials, nblk_line, n);
    lbfgs_solve<<<dim3(1), dim3(256), 0, stream>>>(partials, nblk_line, Lmat,
                                                   diag, sinner, idxp, coeff);
    lbfgs_output<<<dim3(OUTBLK), dim3(256), 0, stream>>>(p, y, g, coeff, out, n);
  } else {
    int nblk = 1024;
    long avail = (long)(ws_size / sizeof(float)) - 64;
    long cap = avail / RED_VALS;
    if (cap < nblk) nblk = (int)(cap < 1 ? 1 : cap);
    float* partials = wsf;
    float* coeff = wsf + (size_t)RED_VALS * nblk;
    lbfgs_reduce_loop<<<dim3(nblk), dim3(256), 0, stream>>>(
        p, y, g, idxp, partials, nblk, n);
    lbfgs_solve<<<dim3(1), dim3(256), 0, stream>>>(partials, nblk, Lmat,
                                                   diag, sinner, idxp, coeff);
    lbfgs_output<<<dim3(OUTBLK), dim3(256), 0, stream>>>(p, y, g, coeff, out, n);
  }
}

// Round 7
// 232.477 us; speedup vs baseline: 1.8285x; 1.8285x over previous
//
#include <hip/hip_runtime.h>

#define HH 16
#define RED_VALS 34   // 16 top(g.p) + 16 (y.p) + cur + gg
#define OUTBLK 2048
#define RBLK 977      // reduce blocks: ceil(1e6 chunks / (256*4)) -> K=4 bursts/thread

// Burst reduction: each thread runs K straight-line bursts. Per burst: load
// all 33 float4s into registers, sched_barrier pins them above the FMAs
// (forces a 33-deep load burst — the property that beat the loop-carried
// variants), accumulate into 34 persistent accumulators. Epilogue (34
// wave-shuffle reductions) paid once per thread, amortized over K bursts.
__global__ __launch_bounds__(256) void lbfgs_reduce_line(
    const float* __restrict__ p, const float* __restrict__ y,
    const float* __restrict__ g, const int* __restrict__ idxp,
    float* __restrict__ partials, int nblk, int n) {
  const int nchunk = n >> 2;
  const int is = idxp[0];
  const int hidx = ((is - 1) % HH + HH) % HH;
  const int K = (nchunk + (gridDim.x << 8) - 1) / (gridDim.x << 8);

  float accg[HH], accy[HH];
#pragma unroll
  for (int i = 0; i < HH; ++i) { accg[i] = 0.f; accy[i] = 0.f; }
  float ac = 0.f, agg = 0.f;

  for (int k = 0; k < K; ++k) {
    const int c = (blockIdx.x + k * gridDim.x) * 256 + threadIdx.x;
    if (c < nchunk) {
      const float4 pv = reinterpret_cast<const float4*>(p)[c];
      float4 gv[HH], yv[HH];
#pragma unroll
      for (int i = 0; i < HH; ++i)
        gv[i] = reinterpret_cast<const float4*>(g + (size_t)i * n)[c];
#pragma unroll
      for (int i = 0; i < HH; ++i)
        yv[i] = reinterpret_cast<const float4*>(y + (size_t)i * n)[c];
      __builtin_amdgcn_sched_barrier(0);  // keep all 33 loads above the FMAs
#pragma unroll
      for (int i = 0; i < HH; ++i) {
        accg[i] += gv[i].x * pv.x + gv[i].y * pv.y + gv[i].z * pv.z + gv[i].w * pv.w;
        accy[i] += yv[i].x * pv.x + yv[i].y * pv.y + yv[i].z * pv.z + yv[i].w * pv.w;
        float dyg = yv[i].x * gv[i].x + yv[i].y * gv[i].y +
                    yv[i].z * gv[i].z + yv[i].w * gv[i].w;
        float dgg = gv[i].x * gv[i].x + gv[i].y * gv[i].y +
                    gv[i].z * gv[i].z + gv[i].w * gv[i].w;
        ac  += (i == hidx) ? dyg : 0.f;   // branchless, hidx wave-uniform
        agg += (i == hidx) ? dgg : 0.f;
      }
    }
  }
  // scalar remainder (n % 4 != 0), handled by block 0 only
  if (blockIdx.x == 0) {
    for (int e = (nchunk << 2) + threadIdx.x; e < n; e += 256) {
      float pv = p[e];
#pragma unroll
      for (int i = 0; i < HH; ++i) {
        float gs = g[(size_t)i * n + e], ys = y[(size_t)i * n + e];
        accg[i] += gs * pv;
        accy[i] += ys * pv;
        ac  += (i == hidx) ? ys * gs : 0.f;
        agg += (i == hidx) ? gs * gs : 0.f;
      }
    }
  }

  // wave(64) shuffle reduce, then cross-wave via LDS; block writes 34 values
  __shared__ float red[4][RED_VALS];
  const int wave = threadIdx.x >> 6, lane = threadIdx.x & 63;
#pragma unroll
  for (int i = 0; i < HH; ++i) {
    float v = accg[i];
#pragma unroll
    for (int off = 32; off > 0; off >>= 1) v += __shfl_down(v, off);
    if (lane == 0) red[wave][i] = v;
    float w = accy[i];
#pragma unroll
    for (int off = 32; off > 0; off >>= 1) w += __shfl_down(w, off);
    if (lane == 0) red[wave][HH + i] = w;
  }
  {
    float v = ac;
#pragma unroll
    for (int off = 32; off > 0; off >>= 1) v += __shfl_down(v, off);
    if (lane == 0) red[wave][32] = v;
    float w = agg;
#pragma unroll
    for (int off = 32; off > 0; off >>= 1) w += __shfl_down(w, off);
    if (lane == 0) red[wave][33] = w;
  }
  __syncthreads();
  if (threadIdx.x < RED_VALS) {
    float s = red[0][threadIdx.x] + red[1][threadIdx.x] +
              red[2][threadIdx.x] + red[3][threadIdx.x];
    // column-major [RED_VALS][nblk]: stage2 block j reads a contiguous row
    partials[(size_t)threadIdx.x * nblk + blockIdx.x] = s;
  }
}

// Stage 2: 34 blocks, block j sums partials[j][0..nblk) (contiguous,
// coalesced) -> sums[j]. Removes the single-block latency-chase that cost
// 212 us in R6.
__global__ __launch_bounds__(256) void lbfgs_stage2(
    const float* __restrict__ partials, int nblk, float* __restrict__ sums) {
  const int j = blockIdx.x;
  float v = 0.f;
  for (int b = threadIdx.x; b < nblk; b += 256)
    v += partials[(size_t)j * nblk + b];
#pragma unroll
  for (int off = 32; off > 0; off >>= 1) v += __shfl_down(v, off);
  __shared__ float red[4];
  const int wave = threadIdx.x >> 6, lane = threadIdx.x & 63;
  if (lane == 0) red[wave] = v;
  __syncthreads();
  if (threadIdx.x == 0)
    sums[j] = red[0] + red[1] + red[2] + red[3];
}

__global__ __launch_bounds__(256) void lbfgs_solve(
    const float* __restrict__ sums_g,
    const float* __restrict__ Lmat, const float* __restrict__ diag,
    const float* __restrict__ sinner, const int* __restrict__ idxp,
    float* __restrict__ coeff) {
  __shared__ float sums[RED_VALS];
  if (threadIdx.x < RED_VALS) sums[threadIdx.x] = sums_g[threadIdx.x];
  __syncthreads();

  __shared__ float Lsh[HH][HH];
  __shared__ float dd[HH], sqd[HH];
  __shared__ float Jsq[HH][HH];
  __shared__ float gamma_s;
  __shared__ float x[2 * HH];
  {
    int i = threadIdx.x >> 4, j = threadIdx.x & 15;
    if (threadIdx.x < 256) Lsh[i][j] = Lmat[i * HH + j];
  }
  if (threadIdx.x < HH) {
    float dv = diag[threadIdx.x];
    float ddv = (dv == 0.f) ? 1.f : dv;
    dd[threadIdx.x] = ddv;
    sqd[threadIdx.x] = sqrtf(ddv);
  }
  if (threadIdx.x == 0) {
    float cur = sums[32], gg = sums[33];
    gamma_s = (cur > 0.f) ? (gg / cur) : 1.f;
  }
  __syncthreads();
  {
    int i = threadIdx.x >> 4, j = threadIdx.x & 15;
    float v = gamma_s * sinner[i * HH + j];
#pragma unroll
    for (int k = 0; k < HH; ++k) v += Lsh[i][k] * Lsh[j][k] / dd[k];
    Jsq[i][j] = v;
  }
  __syncthreads();
  if (threadIdx.x == 0) {
    // in-place lower Cholesky of Jsq (16x16, serial — tiny)
    for (int c = 0; c < HH; ++c) {
      float s = Jsq[c][c];
      for (int k = 0; k < c; ++k) s -= Jsq[c][k] * Jsq[c][k];
      float dv = sqrtf(s);
      Jsq[c][c] = dv;
      float inv = 1.f / dv;
      for (int r = c + 1; r < HH; ++r) {
        float s2 = Jsq[r][c];
        for (int k = 0; k < c; ++k) s2 -= Jsq[r][k] * Jsq[c][k];
        Jsq[r][c] = s2 * inv;
      }
    }
    const int is = idxp[0];
    const int sh = (is <= HH) ? 0 : (is % HH);
    const float gamma = gamma_s;
    // build rolled descent vector
    for (int k = 0; k < HH; ++k) {
      x[k]      = sums[(k + sh) & (HH - 1)];
      x[HH + k] = gamma * sums[HH + ((k + sh) & (HH - 1))];
    }
    // forward solve: low_tri = [[diag(sqd), 0], [-L/sqd_col, J]]
    for (int i = 0; i < HH; ++i) x[i] /= sqd[i];
    for (int i = 0; i < HH; ++i) {
      float s = x[HH + i];
      for (int j = 0; j < HH; ++j) s += (Lsh[i][j] / sqd[j]) * x[j];
      for (int j = 0; j < i; ++j) s -= Jsq[i][j] * x[HH + j];
      x[HH + i] = s / Jsq[i][i];
    }
    // backward solve: upper = low^T with top h rows negated
    for (int i = HH - 1; i >= 0; --i) {
      float s = x[HH + i];
      for (int j = i + 1; j < HH; ++j) s -= Jsq[j][i] * x[HH + j];
      x[HH + i] = s / Jsq[i][i];
    }
    for (int i = 0; i < HH; ++i) {
      float s = x[i];
      for (int j = 0; j < HH; ++j) s -= (Lsh[j][i] / sqd[i]) * x[HH + j];
      x[i] = s / (-sqd[i]);
    }
    // un-roll and emit coefficients (beta pre-scaled by gamma)
    coeff[0] = gamma;
    for (int k = 0; k < HH; ++k) {
      coeff[1 + k]      = x[(k - sh + HH) & (HH - 1)];
      coeff[1 + HH + k] = gamma * x[HH + ((k - sh + HH) & (HH - 1))];
    }
  }
}

// Plain ascending grid-stride (proven ~6.8 TB/s form).
__global__ __launch_bounds__(256) void lbfgs_output(
    const float* __restrict__ p, const float* __restrict__ y,
    const float* __restrict__ g, const float* __restrict__ coeff,
    float* __restrict__ out, int n) {
  const float gamma = coeff[0];
  float a[HH], b[HH];
#pragma unroll
  for (int i = 0; i < HH; ++i) {
    a[i] = coeff[1 + i];
    b[i] = coeff[1 + HH + i];
  }
  const int tid = blockIdx.x * blockDim.x + threadIdx.x;
  const int nth = gridDim.x * blockDim.x;
  const int nchunk = n >> 2;
  const float4* __restrict__ p4 = reinterpret_cast<const float4*>(p);
  float4* __restrict__ out4 = reinterpret_cast<float4*>(out);
  for (int c = tid; c < nchunk; c += nth) {
    float4 pv = p4[c];
    float ox = gamma * pv.x, oy = gamma * pv.y;
    float oz = gamma * pv.z, ow = gamma * pv.w;
#pragma unroll
    for (int i = 0; i < HH; ++i) {
      const float4 gv = reinterpret_cast<const float4*>(g + (size_t)i * n)[c];
      const float4 yv = reinterpret_cast<const float4*>(y + (size_t)i * n)[c];
      ox -= a[i] * gv.x + b[i] * yv.x;
      oy -= a[i] * gv.y + b[i] * yv.y;
      oz -= a[i] * gv.z + b[i] * yv.z;
      ow -= a[i] * gv.w + b[i] * yv.w;
    }
    out4[c] = make_float4(ox, oy, oz, ow);
  }
  for (int c = (nchunk << 2) + tid; c < n; c += nth) {
    float pv = p[c];
    float o = gamma * pv;
#pragma unroll
    for (int i = 0; i < HH; ++i)
      o -= a[i] * g[(size_t)i * n + c] + b[i] * y[(size_t)i * n + c];
    out[c] = o;
  }
}

extern "C" void kernel_launch(void* const* d_in, const int* in_sizes, int n_in,
                              void* d_out, int out_size, void* d_ws, size_t ws_size,
                              hipStream_t stream) {
  const float* p      = (const float*)d_in[0];
  const float* y      = (const float*)d_in[1];
  const float* g      = (const float*)d_in[2];
  const float* Lmat   = (const float*)d_in[3];
  const float* diag   = (const float*)d_in[4];
  const float* sinner = (const float*)d_in[5];
  const int*   idxp   = (const int*)d_in[6];
  float* out = (float*)d_out;
  float* wsf = (float*)d_ws;
  const int n = in_sizes[0];

  // workspace: partials[RED_VALS][nblk] + sums[RED_VALS] + coeff[33]
  int nblk = RBLK;
  {
    long avail = (long)(ws_size / sizeof(float)) - RED_VALS - 64;
    long cap = avail / RED_VALS;
    if (cap < nblk) nblk = (int)(cap < 1 ? 1 : cap);
  }
  float* partials = wsf;
  float* sums     = wsf + (size_t)RED_VALS * nblk;
  float* coeff    = sums + RED_VALS;

  lbfgs_reduce_line<<<dim3(nblk), dim3(256), 0, stream>>>(
      p, y, g, idxp, partials, nblk, n);
  lbfgs_stage2<<<dim3(RED_VALS), dim3(256), 0, stream>>>(partials, nblk, sums);
  lbfgs_solve<<<dim3(1), dim3(256), 0, stream>>>(sums, Lmat, diag,
                                                 sinner, idxp, coeff);
  lbfgs_output<<<dim3(OUTBLK), dim3(256), 0, stream>>>(p, y, g, coeff, out, n);
}